// Round 1
// baseline (1408.759 us; speedup 1.0000x reference)
//
#include <hip/hip_runtime.h>
#include <math.h>

#define BB 64
#define NN 207
#define TT 12
#define NC 10
#define NTOT (BB*NN*TT)     // 158976
#define TRI 21528           // 207*208/2 packed lower triangle
#define SROW 13248          // 207*64 RHS plane

// ws layout (float offsets). Total 2,027,512 floats = 8.11 MB (assumes ws_size >= 8.2MB).
#define KS_OFF   0          // [C][N][N]       428490
#define DT_OFF   428490     // [C][T]          120
#define UT_OFF   428610     // [C][T][T]       1440
#define ULOG_OFF 430050     // [C]             10
#define VLOG_OFF 430060     // [C]             10
#define ACC_OFF  430070     // mask_sum, abs_sum
#define Y_OFF    430072     // [C][T][N][B]    1589760
#define SSQ_OFF  2019832    // [C][T][B]       7680

// round-robin tournament pairing: 12 players, 11 rounds, 6 disjoint pairs/round
__device__ inline void jpair(int r, int pi, int& p, int& q) {
    if (pi == 0) { p = 11; q = r % 11; }
    else { p = (r + pi) % 11; q = (r + 11 - pi) % 11; }
}

// Kernel A: Kt = Lt*Lt^T per component, 12x12 Jacobi eigh (all 10 components in
// one block), logdets from input Cholesky diagonals, zero MAE accumulators.
__global__ __launch_bounds__(256) void kA(const float* __restrict__ Ls,
                                          const float* __restrict__ Lt,
                                          float* __restrict__ ws) {
    __shared__ float Kt[1440], V[1440], rc[60], rs[60];
    int t = threadIdx.x;
    for (int u = t; u < 1440; u += 256) {
        int c = u / 144, rcol = u % 144, i = rcol / 12, j = rcol % 12;
        int kmax = (i < j) ? i : j;
        const float* a = Lt + c*144 + i*12;
        const float* b = Lt + c*144 + j*12;
        float s = 0.f;
        for (int k = 0; k <= kmax; ++k) s += a[k]*b[k];
        Kt[u] = s;
        V[u] = (i == j) ? 1.f : 0.f;
    }
    __syncthreads();
    for (int sweep = 0; sweep < 7; ++sweep)
    for (int r = 0; r < 11; ++r) {
        if (t < 60) {  // angles for 10 comps x 6 disjoint pairs
            int c = t / 6, pi = t % 6, p, q;
            jpair(r, pi, p, q);
            float app = Kt[c*144 + p*13];
            float aqq = Kt[c*144 + q*13];
            float apq = Kt[c*144 + p*12 + q];
            float cs = 1.f, sn = 0.f;
            if (fabsf(apq) > 1e-30f) {
                float tau = (aqq - app) / (2.f * apq);
                float tt = ((tau >= 0.f) ? 1.f : -1.f) / (fabsf(tau) + sqrtf(1.f + tau*tau));
                cs = 1.f / sqrtf(1.f + tt*tt);
                sn = tt * cs;
            }
            rc[t] = cs; rs[t] = sn;
        }
        __syncthreads();
        for (int u = t; u < 720; u += 256) {      // phase 1: B = J^T A (rows p,q)
            int c = u / 72, v = u % 72, pi = v / 12, k = v % 12, p, q;
            jpair(r, pi, p, q);
            float cs = rc[c*6+pi], sn = rs[c*6+pi];
            float x = Kt[c*144 + p*12 + k], y = Kt[c*144 + q*12 + k];
            Kt[c*144 + p*12 + k] = cs*x - sn*y;
            Kt[c*144 + q*12 + k] = sn*x + cs*y;
        }
        __syncthreads();
        for (int u = t; u < 1440; u += 256) {     // phase 2: A' = B J (cols), + V = V J
            int isV = (u >= 720);
            int v2 = isV ? u - 720 : u;
            int c = v2 / 72, v = v2 % 72, pi = v / 12, k = v % 12, p, q;
            jpair(r, pi, p, q);
            float cs = rc[c*6+pi], sn = rs[c*6+pi];
            float* M = isV ? V : Kt;
            float x = M[c*144 + k*12 + p], y = M[c*144 + k*12 + q];
            M[c*144 + k*12 + p] = cs*x - sn*y;
            M[c*144 + k*12 + q] = sn*x + cs*y;
        }
        __syncthreads();
    }
    for (int u = t; u < 1440; u += 256) ws[UT_OFF + u] = V[u];
    if (t < 120) ws[DT_OFF + t] = Kt[(t/12)*144 + (t%12)*13];
    if (t < NC) {
        float su = 0.f;
        for (int i = 0; i < NN; ++i) su += logf(Ls[t*(NN*NN) + i*(NN+1)]);
        ws[ULOG_OFF + t] = su;
        float sv = 0.f;
        for (int i = 0; i < TT; ++i) sv += logf(Lt[t*144 + i*13]);
        ws[VLOG_OFF + t] = sv;
    }
    if (t < 2) ws[ACC_OFF + t] = 0.f;
}

// Kernel B: Ks[c] = Ls[c] * Ls[c]^T (full square; kD reads lower only)
__global__ __launch_bounds__(256) void kB(const float* __restrict__ Ls,
                                          float* __restrict__ Ks) {
    int c = blockIdx.x / NN, i = blockIdx.x % NN;
    int j = threadIdx.x;
    if (j < NN) {
        const float* ri = Ls + (size_t)(c*NN + i)*NN;
        const float* rj = Ls + (size_t)(c*NN + j)*NN;
        int kmax = (i < j) ? i : j;
        float s = 0.f;
        for (int k = 0; k <= kmax; ++k) s += ri[k]*rj[k];
        Ks[(size_t)(c*NN + i)*NN + j] = s;
    }
}

// Kernel C: Y[c][j][i][b] = sum_q (target-mu)[b,i,q] * Ut[c][q][j]
__global__ __launch_bounds__(256) void kC(const float* __restrict__ mu,
                                          const float* __restrict__ tg,
                                          const float* __restrict__ Ut,
                                          float* __restrict__ Y) {
    __shared__ float U[144];
    int t = threadIdx.x;
    int c = blockIdx.x >> 6, b = blockIdx.x & 63;
    if (t < 144) U[t] = Ut[c*144 + t];
    __syncthreads();
    if (t < NN) {
        const float* mp = mu + (size_t)(b*NN + t)*TT;
        const float* tp = tg + (size_t)(b*NN + t)*TT;
        float rr[TT];
        #pragma unroll
        for (int q = 0; q < TT; ++q) rr[q] = tp[q] - mp[q];
        #pragma unroll
        for (int j = 0; j < TT; ++j) {
            float y = 0.f;
            #pragma unroll
            for (int q = 0; q < TT; ++q) y += rr[q] * U[q*12 + j];
            Y[((size_t)(c*TT + j)*NN + t)*64 + b] = y;
        }
    }
}

// Kernel R: masked MAE sums (mask count, sum |mu-target|*mask)
__global__ __launch_bounds__(256) void kR(const float* __restrict__ mu,
                                          const float* __restrict__ tg,
                                          const float* __restrict__ uns,
                                          float* __restrict__ acc) {
    int gid = blockIdx.x*256 + threadIdx.x;
    float u = uns[gid];
    float mk = (u != 0.0f) ? 1.f : 0.f;
    float d = fabsf(mu[gid] - tg[gid]) * mk;
    for (int o = 32; o > 0; o >>= 1) {
        mk += __shfl_down(mk, o, 64);
        d  += __shfl_down(d,  o, 64);
    }
    if ((threadIdx.x & 63) == 0) {
        atomicAdd(&acc[0], mk);
        atomicAdd(&acc[1], d);
    }
}

// Kernel D: per (c,j): Cholesky of A = Dt[c,j]*Ks_c + sigma_c^2 I (packed lower
// triangle in LDS) fused with forward substitution for 64 RHS; emits ||L^-1 y||^2.
__global__ __launch_bounds__(256) void kD(const float* __restrict__ Ks,
                                          const float* __restrict__ Dt,
                                          const float* __restrict__ sig,
                                          const float* __restrict__ Y,
                                          float* __restrict__ ssq) {
    extern __shared__ float lds[];
    float* Apk = lds;            // TRI
    float* S   = lds + TRI;      // SROW, S[i*64+b]
    float* zb  = S + SROW;       // 64
    int t = threadIdx.x;
    int c = blockIdx.x / TT, j = blockIdx.x % TT;
    float dt = Dt[c*TT + j];
    float sg = sig[c], sg2 = sg*sg;
    const float* KsC = Ks + (size_t)c*NN*NN;
    for (int f = t; f < TRI; f += 256) {
        int i = (int)((sqrtf(8.f*(float)f + 1.f) - 1.f)*0.5f);
        while ((i+1)*(i+2)/2 <= f) ++i;
        while (i*(i+1)/2 > f) --i;
        int jj = f - i*(i+1)/2;
        float v = dt * KsC[i*NN + jj];
        if (i == jj) v += sg2;
        Apk[f] = v;
    }
    const float* Yp = Y + (size_t)(c*TT + j)*SROW;
    for (int f = t; f < SROW; f += 256) S[f] = Yp[f];
    float zacc = 0.f;
    __syncthreads();
    int tr = t >> 4, tc = t & 15;
    for (int k = 0; k < NN; ++k) {
        int rowk = (k*(k+1)) >> 1;
        float diag = Apk[rowk + k];          // finalized; nobody writes it this region
        float dinv = 1.0f / sqrtf(diag);
        for (int i = k+1+t; i < NN; i += 256) Apk[((i*(i+1))>>1) + k] *= dinv;
        if (t < 64) {
            float z = S[k*64 + t] * dinv;    // z_k = s_k / L[k,k]
            zacc += z*z;
            zb[t] = z;
        }
        __syncthreads();
        // trailing rank-1 update, 16x16 thread tile over lower triangle
        for (int i = k+1+tr; i < NN; i += 16) {
            int ro = (i*(i+1)) >> 1;
            float li = Apk[ro + k];
            for (int jj2 = k+1+tc; jj2 <= i; jj2 += 16)
                Apk[ro + jj2] -= li * Apk[((jj2*(jj2+1))>>1) + k];
        }
        // RHS update for all 64 systems
        int m = NN - 1 - k;
        for (int f = t; f < (m << 6); f += 256) {
            int b = f & 63, rr2 = k + 1 + (f >> 6);
            S[rr2*64 + b] -= Apk[((rr2*(rr2+1))>>1) + k] * zb[b];
        }
        __syncthreads();
    }
    if (t < 64) ssq[(blockIdx.x << 6) + t] = zacc;
}

// Kernel E: quad -> ll -> logsumexp -> mean; combine with MAE; scalar out.
__global__ __launch_bounds__(256) void kE(const float* __restrict__ ssq,
                                          const float* __restrict__ Ulog,
                                          const float* __restrict__ Vlog,
                                          const float* __restrict__ w,
                                          const float* __restrict__ acc,
                                          float* __restrict__ out) {
    __shared__ float llds[640], nl[64];
    const float C0 = -0.5f * 2484.0f * 1.8378770664093453f;
    int t = threadIdx.x;
    for (int u = t; u < 640; u += 256) {
        int b = u / NC, c = u % NC;
        float q = 0.f;
        for (int j = 0; j < TT; ++j) q += ssq[(c*TT + j)*64 + b];
        llds[u] = C0 - 0.5f*q + 207.f*Vlog[c] + 12.f*Ulog[c] + logf(w[b*NC + c]);
    }
    __syncthreads();
    if (t < 64) {
        float mx = -1e30f;
        for (int c = 0; c < NC; ++c) mx = fmaxf(mx, llds[t*NC + c]);
        float s = 0.f;
        for (int c = 0; c < NC; ++c) s += expf(llds[t*NC + c] - mx);
        nl[t] = -(mx + logf(s));
    }
    __syncthreads();
    if (t < 64) {
        float v = nl[t];
        for (int o = 32; o > 0; o >>= 1) v += __shfl_down(v, o, 64);
        if (t == 0) {
            float sm = acc[0], sa = acc[1];
            float mse = (sm > 0.f) ? sa / sm : 0.f;
            out[0] = 0.1f * (v * (1.f/64.f)) + 0.9f * mse;
        }
    }
}

extern "C" void kernel_launch(void* const* d_in, const int* in_sizes, int n_in,
                              void* d_out, int out_size, void* d_ws, size_t ws_size,
                              hipStream_t stream) {
    const float* mu  = (const float*)d_in[0];
    const float* tg  = (const float*)d_in[1];
    const float* uns = (const float*)d_in[2];
    const float* w   = (const float*)d_in[3];
    const float* sig = (const float*)d_in[4];
    // d_in[5] = R, unused by the reference loss
    const float* Ls  = (const float*)d_in[6];
    const float* Lt  = (const float*)d_in[7];
    float* out = (float*)d_out;
    float* ws  = (float*)d_ws;

    const int kd_lds = (TRI + SROW + 64) * 4;   // 139,360 B < 160 KiB
    (void)hipFuncSetAttribute((const void*)kD,
                              hipFuncAttributeMaxDynamicSharedMemorySize, kd_lds);

    kA<<<1, 256, 0, stream>>>(Ls, Lt, ws);
    kB<<<NC*NN, 256, 0, stream>>>(Ls, ws + KS_OFF);
    kC<<<NC*BB, 256, 0, stream>>>(mu, tg, ws + UT_OFF, ws + Y_OFF);
    kR<<<NTOT/256, 256, 0, stream>>>(mu, tg, uns, ws + ACC_OFF);
    kD<<<NC*TT, 256, kd_lds, stream>>>(ws + KS_OFF, ws + DT_OFF, sig, ws + Y_OFF, ws + SSQ_OFF);
    kE<<<1, 256, 0, stream>>>(ws + SSQ_OFF, ws + ULOG_OFF, ws + VLOG_OFF, w, ws + ACC_OFF, out);
}

// Round 2
// 660.318 us; speedup vs baseline: 2.1335x; 2.1335x over previous
//
#include <hip/hip_runtime.h>
#include <math.h>

#define BB 64
#define NN 207
#define TT 12
#define NC 10
#define NTOT (BB*NN*TT)     // 158976
#define NP 208              // padded matrix dim (pad row 207: identity)
#define TRI8 21736          // 208*209/2 packed lower triangle
#define WST 209             // W row stride (odd -> full bank spread)
#define PTS 272             // Pt row stride (rows k1..207 + 64 W rows at 208..271)

// ws layout (float offsets). Total 2,027,512 floats = 8.11 MB (same as R1).
#define KS_OFF   0          // [C][N][N]       428490
#define DT_OFF   428490     // [C][T]          120
#define UT_OFF   428610     // [C][T][T]       1440
#define ULOG_OFF 430050     // [C]             10
#define VLOG_OFF 430060     // [C]             10
#define ACC_OFF  430070     // mask_sum, abs_sum
#define Y_OFF    430072     // [C][T][B][N]    1589760  (b-major now)
#define SSQ_OFF  2019832    // [C][T][B]       7680

// round-robin tournament pairing: 12 players, 11 rounds, 6 disjoint pairs/round
__device__ inline void jpair(int r, int pi, int& p, int& q) {
    if (pi == 0) { p = 11; q = r % 11; }
    else { p = (r + pi) % 11; q = (r + 11 - pi) % 11; }
}

// Kernel A: Kt = Lt*Lt^T per component, 12x12 Jacobi eigh (all 10 components in
// one block), logdets from input Cholesky diagonals, zero MAE accumulators.
__global__ __launch_bounds__(256) void kA(const float* __restrict__ Ls,
                                          const float* __restrict__ Lt,
                                          float* __restrict__ ws) {
    __shared__ float Kt[1440], V[1440], rc[60], rs[60];
    int t = threadIdx.x;
    for (int u = t; u < 1440; u += 256) {
        int c = u / 144, rcol = u % 144, i = rcol / 12, j = rcol % 12;
        int kmax = (i < j) ? i : j;
        const float* a = Lt + c*144 + i*12;
        const float* b = Lt + c*144 + j*12;
        float s = 0.f;
        for (int k = 0; k <= kmax; ++k) s += a[k]*b[k];
        Kt[u] = s;
        V[u] = (i == j) ? 1.f : 0.f;
    }
    __syncthreads();
    for (int sweep = 0; sweep < 7; ++sweep)
    for (int r = 0; r < 11; ++r) {
        if (t < 60) {
            int c = t / 6, pi = t % 6, p, q;
            jpair(r, pi, p, q);
            float app = Kt[c*144 + p*13];
            float aqq = Kt[c*144 + q*13];
            float apq = Kt[c*144 + p*12 + q];
            float cs = 1.f, sn = 0.f;
            if (fabsf(apq) > 1e-30f) {
                float tau = (aqq - app) / (2.f * apq);
                float tt = ((tau >= 0.f) ? 1.f : -1.f) / (fabsf(tau) + sqrtf(1.f + tau*tau));
                cs = 1.f / sqrtf(1.f + tt*tt);
                sn = tt * cs;
            }
            rc[t] = cs; rs[t] = sn;
        }
        __syncthreads();
        for (int u = t; u < 720; u += 256) {      // rows p,q
            int c = u / 72, v = u % 72, pi = v / 12, k = v % 12, p, q;
            jpair(r, pi, p, q);
            float cs = rc[c*6+pi], sn = rs[c*6+pi];
            float x = Kt[c*144 + p*12 + k], y = Kt[c*144 + q*12 + k];
            Kt[c*144 + p*12 + k] = cs*x - sn*y;
            Kt[c*144 + q*12 + k] = sn*x + cs*y;
        }
        __syncthreads();
        for (int u = t; u < 1440; u += 256) {     // cols + V
            int isV = (u >= 720);
            int v2 = isV ? u - 720 : u;
            int c = v2 / 72, v = v2 % 72, pi = v / 12, k = v % 12, p, q;
            jpair(r, pi, p, q);
            float cs = rc[c*6+pi], sn = rs[c*6+pi];
            float* M = isV ? V : Kt;
            float x = M[c*144 + k*12 + p], y = M[c*144 + k*12 + q];
            M[c*144 + k*12 + p] = cs*x - sn*y;
            M[c*144 + k*12 + q] = sn*x + cs*y;
        }
        __syncthreads();
    }
    for (int u = t; u < 1440; u += 256) ws[UT_OFF + u] = V[u];
    if (t < 120) ws[DT_OFF + t] = Kt[(t/12)*144 + (t%12)*13];
    if (t < NC) {
        float su = 0.f;
        for (int i = 0; i < NN; ++i) su += logf(Ls[t*(NN*NN) + i*(NN+1)]);
        ws[ULOG_OFF + t] = su;
        float sv = 0.f;
        for (int i = 0; i < TT; ++i) sv += logf(Lt[t*144 + i*13]);
        ws[VLOG_OFF + t] = sv;
    }
    if (t < 2) ws[ACC_OFF + t] = 0.f;
}

// Kernel B: Ks[c] = Ls[c] * Ls[c]^T
__global__ __launch_bounds__(256) void kB(const float* __restrict__ Ls,
                                          float* __restrict__ Ks) {
    int c = blockIdx.x / NN, i = blockIdx.x % NN;
    int j = threadIdx.x;
    if (j < NN) {
        const float* ri = Ls + (size_t)(c*NN + i)*NN;
        const float* rj = Ls + (size_t)(c*NN + j)*NN;
        int kmax = (i < j) ? i : j;
        float s = 0.f;
        for (int k = 0; k <= kmax; ++k) s += ri[k]*rj[k];
        Ks[(size_t)(c*NN + i)*NN + j] = s;
    }
}

// Kernel C: Y[c][j][b][i] = sum_q (target-mu)[b,i,q] * Ut[c][q][j]  (b-major)
__global__ __launch_bounds__(256) void kC(const float* __restrict__ mu,
                                          const float* __restrict__ tg,
                                          const float* __restrict__ Ut,
                                          float* __restrict__ Y) {
    __shared__ float U[144];
    int t = threadIdx.x;
    int c = blockIdx.x >> 6, b = blockIdx.x & 63;
    if (t < 144) U[t] = Ut[c*144 + t];
    __syncthreads();
    if (t < NN) {
        const float* mp = mu + (size_t)(b*NN + t)*TT;
        const float* tp = tg + (size_t)(b*NN + t)*TT;
        float rr[TT];
        #pragma unroll
        for (int q = 0; q < TT; ++q) rr[q] = tp[q] - mp[q];
        #pragma unroll
        for (int j = 0; j < TT; ++j) {
            float y = 0.f;
            #pragma unroll
            for (int q = 0; q < TT; ++q) y += rr[q] * U[q*12 + j];
            Y[((size_t)(c*TT + j)*64 + b)*NN + t] = y;
        }
    }
}

// Kernel R: masked MAE sums
__global__ __launch_bounds__(256) void kR(const float* __restrict__ mu,
                                          const float* __restrict__ tg,
                                          const float* __restrict__ uns,
                                          float* __restrict__ acc) {
    int gid = blockIdx.x*256 + threadIdx.x;
    float u = uns[gid];
    float mk = (u != 0.0f) ? 1.f : 0.f;
    float d = fabsf(mu[gid] - tg[gid]) * mk;
    for (int o = 32; o > 0; o >>= 1) {
        mk += __shfl_down(mk, o, 64);
        d  += __shfl_down(d,  o, 64);
    }
    if ((threadIdx.x & 63) == 0) {
        atomicAdd(&acc[0], mk);
        atomicAdd(&acc[1], d);
    }
}

// Kernel D: blocked (P=16) Cholesky of A = Dt[c,j]*Ks_c + sig^2 I, fused with
// forward substitution: 64 RHS appended as trapezoid rows (W). Panel pipeline:
//   wave0 register-factor of 16x16 diag (shuffle broadcasts, no barriers)
//   -> unified row-solve (<=256 rows, 1/thread) writing transposed panel Pt
//   -> register-tiled rank-16 SYRK trailing update via ds_read_b128 on Pt.
// 3 barriers/panel * 13 panels (vs 414 in R1).
__global__ __launch_bounds__(256) void kD(const float* __restrict__ Ks,
                                          const float* __restrict__ Dtv,
                                          const float* __restrict__ sig,
                                          const float* __restrict__ Y,
                                          float* __restrict__ ssq) {
    extern __shared__ float lds[];
    float* Apk = lds;                    // 21736
    float* W   = Apk + TRI8;             // 64*209 = 13376
    float* Pt  = W + 64*WST;             // 16*272 + 64 slack = 4416
    float* ldg = Pt + 16*PTS + 64;       // 256 (diag block L, row-major 16x16)
    float* dnv = ldg + 256;              // 16  (1/L[kk][kk])
    int t = threadIdx.x;
    int c = blockIdx.x / TT;
    float dt = Dtv[blockIdx.x];
    float sg = sig[c], sg2 = sg*sg;
    const float* KsC = Ks + (size_t)c*NN*NN;

    // stage A (padded packed triangle; pad row 207 = e_207)
    for (int f = t; f < TRI8; f += 256) {
        int i = (int)((sqrtf(8.f*(float)f + 1.f) - 1.f)*0.5f);
        while ((i+1)*(i+2)/2 <= f) ++i;
        while (i*(i+1)/2 > f) --i;
        int jj = f - i*(i+1)/2;
        float v;
        if (i == NN) v = (jj == NN) ? 1.f : 0.f;
        else { v = dt * KsC[i*NN + jj]; if (i == jj) v += sg2; }
        Apk[f] = v;
    }
    // stage W rows (RHS), pad col 207 = 0
    const float* Yp = Y + (size_t)blockIdx.x * (64*NN);
    for (int u = t; u < 64*NN; u += 256) {
        int b = u / NN, r = u - b*NN;
        W[b*WST + r] = Yp[u];
    }
    if (t < 64) W[t*WST + NN] = 0.f;
    __syncthreads();

    for (int p = 0; p < 13; ++p) {
        int k0 = p*16, k1 = k0 + 16;
        // ---- 16x16 diag factor, wave 0, registers + shuffles
        if (t < 64) {
            int r = t;
            int rr = (r < 16) ? (k0 + r) : k0;
            int base = ((rr*(rr+1)) >> 1) + k0;
            float a[16];
            #pragma unroll
            for (int m = 0; m < 16; ++m) a[m] = Apk[base + m];
            #pragma unroll
            for (int kk = 0; kk < 16; ++kk) {
                float d = __shfl(a[kk], kk);
                float dv = 1.0f / sqrtf(d);
                if (t == 0) dnv[kk] = dv;
                if (r < 16 && r > kk) a[kk] *= dv;
                #pragma unroll
                for (int j2 = kk+1; j2 < 16; ++j2) {
                    float v = __shfl(a[kk], j2);      // L[j2][kk] from lane j2
                    if (r < 16 && r > kk && j2 <= r) a[j2] -= a[kk]*v;
                }
            }
            if (r < 16) {
                #pragma unroll
                for (int m = 0; m < 16; ++m) ldg[r*16 + m] = a[m];
            }
        }
        __syncthreads();
        // ---- unified panel row solve: below-A rows (incl pad) + 64 W rows
        int nA = NP - k1;
        int nsolve = nA + 64;              // = 256 - 16p  (<= 256)
        if (t < nsolve) {
            bool isW = (t >= nA);
            float arow[16];
            int abase = 0, wb = 0;
            if (!isW) {
                int r = k1 + t;
                abase = ((r*(r+1)) >> 1) + k0;
                #pragma unroll
                for (int m = 0; m < 16; ++m) arow[m] = Apk[abase + m];
            } else {
                wb = t - nA;
                #pragma unroll
                for (int m = 0; m < 16; ++m) arow[m] = W[wb*WST + k0 + m];
            }
            #pragma unroll
            for (int kk = 0; kk < 16; ++kk) {
                float x = arow[kk];
                #pragma unroll
                for (int m = 0; m < kk; ++m) x -= arow[m] * ldg[kk*16 + m];
                arow[kk] = x * dnv[kk];
            }
            int rho = isW ? (NP + wb) : (k1 + t);
            if (!isW) {
                #pragma unroll
                for (int m = 0; m < 16; ++m) Apk[abase + m] = arow[m];
            } else {
                #pragma unroll
                for (int m = 0; m < 16; ++m) W[wb*WST + k0 + m] = arow[m];
            }
            #pragma unroll
            for (int m = 0; m < 16; ++m) Pt[m*PTS + rho] = arow[m];
        }
        __syncthreads();
        // ---- trailing rank-16 update (SYRK over A-triangle + W block)
        int nc2 = NP - k1;                 // trailing cols
        int nr2 = nc2 + 64;                // + W rows; row-space rho in [k1, 272)
        if (nc2 > 0) {
            int ty = t >> 4, tx = t & 15;
            for (int rg = 0; rg < nr2; rg += 64) {
                int rbase = k1 + rg + 4*ty;
                for (int cg = 0; cg < nc2; cg += 64) {
                    int cbase = k1 + cg + 4*tx;
                    if (rbase + 3 < cbase && rbase + 3 < NP) continue; // above diag
                    float acc[4][4];
                    #pragma unroll
                    for (int a2 = 0; a2 < 4; ++a2)
                        #pragma unroll
                        for (int b2 = 0; b2 < 4; ++b2) acc[a2][b2] = 0.f;
                    #pragma unroll
                    for (int kk = 0; kk < 16; ++kk) {
                        float4 av = *(const float4*)(Pt + kk*PTS + rbase);
                        float4 bv = *(const float4*)(Pt + kk*PTS + cbase);
                        acc[0][0] += av.x*bv.x; acc[0][1] += av.x*bv.y;
                        acc[0][2] += av.x*bv.z; acc[0][3] += av.x*bv.w;
                        acc[1][0] += av.y*bv.x; acc[1][1] += av.y*bv.y;
                        acc[1][2] += av.y*bv.z; acc[1][3] += av.y*bv.w;
                        acc[2][0] += av.z*bv.x; acc[2][1] += av.z*bv.y;
                        acc[2][2] += av.z*bv.z; acc[2][3] += av.z*bv.w;
                        acc[3][0] += av.w*bv.x; acc[3][1] += av.w*bv.y;
                        acc[3][2] += av.w*bv.z; acc[3][3] += av.w*bv.w;
                    }
                    #pragma unroll
                    for (int ri2 = 0; ri2 < 4; ++ri2) {
                        int rho = rbase + ri2;
                        if (rho >= NP + 64) continue;
                        #pragma unroll
                        for (int ci2 = 0; ci2 < 4; ++ci2) {
                            int jc = cbase + ci2;
                            if (jc >= NP) continue;
                            if (rho < NP) {
                                if (jc <= rho)
                                    Apk[((rho*(rho+1))>>1) + jc] -= acc[ri2][ci2];
                            } else {
                                W[(rho - NP)*WST + jc] -= acc[ri2][ci2];
                            }
                        }
                    }
                }
            }
        }
        __syncthreads();
    }
    // quad = ||L^-1 y||^2 per batch
    if (t < 64) {
        float s = 0.f;
        for (int k = 0; k < NP; ++k) { float z = W[t*WST + k]; s += z*z; }
        ssq[(blockIdx.x << 6) + t] = s;
    }
}

// Kernel E: quad -> ll -> logsumexp -> mean; combine with MAE; scalar out.
__global__ __launch_bounds__(256) void kE(const float* __restrict__ ssq,
                                          const float* __restrict__ Ulog,
                                          const float* __restrict__ Vlog,
                                          const float* __restrict__ w,
                                          const float* __restrict__ acc,
                                          float* __restrict__ out) {
    __shared__ float llds[640], nl[64];
    const float C0 = -0.5f * 2484.0f * 1.8378770664093453f;
    int t = threadIdx.x;
    for (int u = t; u < 640; u += 256) {
        int b = u / NC, c = u % NC;
        float q = 0.f;
        for (int j = 0; j < TT; ++j) q += ssq[(c*TT + j)*64 + b];
        llds[u] = C0 - 0.5f*q + 207.f*Vlog[c] + 12.f*Ulog[c] + logf(w[b*NC + c]);
    }
    __syncthreads();
    if (t < 64) {
        float mx = -1e30f;
        for (int c = 0; c < NC; ++c) mx = fmaxf(mx, llds[t*NC + c]);
        float s = 0.f;
        for (int c = 0; c < NC; ++c) s += expf(llds[t*NC + c] - mx);
        nl[t] = -(mx + logf(s));
    }
    __syncthreads();
    if (t < 64) {
        float v = nl[t];
        for (int o = 32; o > 0; o >>= 1) v += __shfl_down(v, o, 64);
        if (t == 0) {
            float sm = acc[0], sa = acc[1];
            float mse = (sm > 0.f) ? sa / sm : 0.f;
            out[0] = 0.1f * (v * (1.f/64.f)) + 0.9f * mse;
        }
    }
}

extern "C" void kernel_launch(void* const* d_in, const int* in_sizes, int n_in,
                              void* d_out, int out_size, void* d_ws, size_t ws_size,
                              hipStream_t stream) {
    const float* mu  = (const float*)d_in[0];
    const float* tg  = (const float*)d_in[1];
    const float* uns = (const float*)d_in[2];
    const float* w   = (const float*)d_in[3];
    const float* sig = (const float*)d_in[4];
    // d_in[5] = R, unused by the reference loss
    const float* Ls  = (const float*)d_in[6];
    const float* Lt  = (const float*)d_in[7];
    float* out = (float*)d_out;
    float* ws  = (float*)d_ws;

    const int kd_lds = (TRI8 + 64*WST + 16*PTS + 64 + 256 + 16) * 4; // 159,200 B
    (void)hipFuncSetAttribute((const void*)kD,
                              hipFuncAttributeMaxDynamicSharedMemorySize, kd_lds);

    kA<<<1, 256, 0, stream>>>(Ls, Lt, ws);
    kB<<<NC*NN, 256, 0, stream>>>(Ls, ws + KS_OFF);
    kC<<<NC*BB, 256, 0, stream>>>(mu, tg, ws + UT_OFF, ws + Y_OFF);
    kR<<<NTOT/256, 256, 0, stream>>>(mu, tg, uns, ws + ACC_OFF);
    kD<<<NC*TT, 256, kd_lds, stream>>>(ws + KS_OFF, ws + DT_OFF, sig, ws + Y_OFF, ws + SSQ_OFF);
    kE<<<1, 256, 0, stream>>>(ws + SSQ_OFF, ws + ULOG_OFF, ws + VLOG_OFF, w, ws + ACC_OFF, out);
}